// Round 2
// baseline (3610.598 us; speedup 1.0000x reference)
//
#include <hip/hip_runtime.h>
#include <math.h>

#define T_ 200
#define B_ 256

// ---------------- xg GEMM for one C-timestep chunk, one direction, with the
// embedding gather (char_table[ci] * feat_table[fi]) fused into the A-tile load.
// C[rows x 1024] = emb_chunk[rows x 256] @ Wih^T + bias, rows = C*256.
// tiles: 64(M) x 128(N) x 32(K); 256 threads; micro-tile 4x8.
// Chunk local row r holds timestep t = t0 + sgn*r (sgn=+1 fwd, -1 bwd).
__global__ __launch_bounds__(256) void xg_gemm(
    const int* __restrict__ bin, const int* __restrict__ bfe,
    const float* __restrict__ ctab, const float* __restrict__ ftab,
    const float* __restrict__ wih, const float* __restrict__ bias,
    float* __restrict__ xgslot, int t0, int sgn) {
  __shared__ float As[32][68];    // transposed A tile [k][m]
  __shared__ float Bs[32][132];   // transposed B tile [k][n]
  const int tid = threadIdx.x;
  const int m0 = blockIdx.x * 64;
  const int n0 = blockIdx.y * 128;

  const int mm = tid & 15;
  const int nn = tid >> 4;

  float acc[2][4][4];
  #pragma unroll
  for (int q = 0; q < 2; ++q)
    #pragma unroll
    for (int i = 0; i < 4; ++i)
      #pragma unroll
      for (int j2 = 0; j2 < 4; ++j2) acc[q][i][j2] = 0.f;

  const int ra = tid & 63, ka = tid >> 6;    // A stage: row, 8-k group
  const int rb = tid & 127, kb = tid >> 7;   // B stage: row(n), 16-k group

  // fused gather: indices for this thread's A row (fixed across K-loop)
  const int mrow = m0 + ra;
  const int rloc = mrow >> 8;          // local timestep within chunk
  const int bcol = mrow & 255;         // batch index
  const int t = t0 + sgn * rloc;
  const float* cr = ctab + ((size_t)bin[bcol * T_ + t] << 8);
  const float* fr = ftab + ((size_t)bfe[bcol * T_ + t] << 8);

  for (int ks = 0; ks < 256; ks += 32) {
    {
      const float* c0p = cr + ks + ka * 8;
      const float* f0p = fr + ks + ka * 8;
      float4 c0 = *(const float4*)(c0p);
      float4 c1 = *(const float4*)(c0p + 4);
      float4 f0 = *(const float4*)(f0p);
      float4 f1 = *(const float4*)(f0p + 4);
      int kk = ka * 8;
      As[kk + 0][ra] = c0.x * f0.x; As[kk + 1][ra] = c0.y * f0.y;
      As[kk + 2][ra] = c0.z * f0.z; As[kk + 3][ra] = c0.w * f0.w;
      As[kk + 4][ra] = c1.x * f1.x; As[kk + 5][ra] = c1.y * f1.y;
      As[kk + 6][ra] = c1.z * f1.z; As[kk + 7][ra] = c1.w * f1.w;
    }
    {
      const float* src = wih + (size_t)(n0 + rb) * 256 + ks + kb * 16;
      float4 v0 = *(const float4*)(src);
      float4 v1 = *(const float4*)(src + 4);
      float4 v2 = *(const float4*)(src + 8);
      float4 v3 = *(const float4*)(src + 12);
      int kk = kb * 16;
      Bs[kk + 0][rb] = v0.x; Bs[kk + 1][rb] = v0.y; Bs[kk + 2][rb] = v0.z; Bs[kk + 3][rb] = v0.w;
      Bs[kk + 4][rb] = v1.x; Bs[kk + 5][rb] = v1.y; Bs[kk + 6][rb] = v1.z; Bs[kk + 7][rb] = v1.w;
      Bs[kk + 8][rb] = v2.x; Bs[kk + 9][rb] = v2.y; Bs[kk +10][rb] = v2.z; Bs[kk +11][rb] = v2.w;
      Bs[kk +12][rb] = v3.x; Bs[kk +13][rb] = v3.y; Bs[kk +14][rb] = v3.z; Bs[kk +15][rb] = v3.w;
    }
    __syncthreads();
    for (int k = 0; k < 32; ++k) {
      float4 av = *(const float4*)&As[k][mm * 4];
      float4 b0 = *(const float4*)&Bs[k][nn * 4];
      float4 b1 = *(const float4*)&Bs[k][64 + nn * 4];
      float am[4] = {av.x, av.y, av.z, av.w};
      float bv[2][4] = {{b0.x, b0.y, b0.z, b0.w}, {b1.x, b1.y, b1.z, b1.w}};
      #pragma unroll
      for (int i = 0; i < 4; ++i)
        #pragma unroll
        for (int q = 0; q < 2; ++q)
          #pragma unroll
          for (int j2 = 0; j2 < 4; ++j2)
            acc[q][i][j2] += am[i] * bv[q][j2];
    }
    __syncthreads();
  }
  #pragma unroll
  for (int q = 0; q < 2; ++q) {
    int nc = n0 + q * 64 + nn * 4;
    float4 bv = *(const float4*)(bias + nc);
    #pragma unroll
    for (int i = 0; i < 4; ++i) {
      int row = m0 + mm * 4 + i;
      float4 o;
      o.x = acc[q][i][0] + bv.x;
      o.y = acc[q][i][1] + bv.y;
      o.z = acc[q][i][2] + bv.z;
      o.w = acc[q][i][3] + bv.w;
      *(float4*)(xgslot + (size_t)row * 1024 + nc) = o;
    }
  }
}

// ---------------- one LSTM timestep (global step s), both directions.
// grid (16 bchunk, 8 jslice, 2 dir), 256 threads.
// fwd processes t=s; bwd processes t=199-s. r = local row in current xg chunk.
__global__ __launch_bounds__(256) void lstm_step(
    const float* __restrict__ xgf, const float* __restrict__ xgb,
    const float* __restrict__ whf, const float* __restrict__ whb,
    const int* __restrict__ blen,
    float* __restrict__ h_state, float* __restrict__ c_state,
    float* __restrict__ h_out, int s, int r) {
  const int bc = blockIdx.x;
  const int js = blockIdx.y;
  const int dir = blockIdx.z;
  const int tid = threadIdx.x;
  const int tt = dir ? (199 - s) : s;
  const int slot = s & 1;

  __shared__ float h_lds[16 * 256];
  __shared__ float red[3][32][64];
  __shared__ float gl[4][32][20];   // [gate][j][b] padded to 20

  const float* hsrc = h_state + (((size_t)(slot * 2 + dir) * 256) + bc * 16) * 256;
  for (int i = tid; i < 1024; i += 256)
    *(float4*)&h_lds[i * 4] = *(const float4*)(hsrc + (size_t)i * 4);
  __syncthreads();

  const int w = tid >> 6;
  const int lane = tid & 63;
  const int j = lane & 31;
  const int qp = lane >> 5;
  const int jg = js * 32 + j;
  const float* wh = dir ? whb : whf;
  const float* w0p = wh + ((size_t)(2 * qp) * 256 + jg) * 256 + w * 64;  // gates {0,2}*256
  const float* w1p = w0p + 65536;                                       // gates {1,3}*256

  float acc0[16], acc1[16];
  #pragma unroll
  for (int b = 0; b < 16; ++b) { acc0[b] = 0.f; acc1[b] = 0.f; }

  for (int kq = 0; kq < 16; ++kq) {
    float4 w0 = *(const float4*)(w0p + kq * 4);
    float4 w1 = *(const float4*)(w1p + kq * 4);
    const int kb2 = w * 64 + kq * 4;
    #pragma unroll
    for (int b = 0; b < 16; ++b) {
      float4 h4 = *(const float4*)&h_lds[b * 256 + kb2];
      acc0[b] += w0.x * h4.x + w0.y * h4.y + w0.z * h4.z + w0.w * h4.w;
      acc1[b] += w1.x * h4.x + w1.y * h4.y + w1.z * h4.z + w1.w * h4.w;
    }
  }

  if (w > 0) {
    #pragma unroll
    for (int b = 0; b < 16; ++b) {
      red[w - 1][b][lane] = acc0[b];
      red[w - 1][16 + b][lane] = acc1[b];
    }
  }
  __syncthreads();
  if (w == 0) {
    #pragma unroll
    for (int u = 0; u < 3; ++u)
      #pragma unroll
      for (int b = 0; b < 16; ++b) {
        acc0[b] += red[u][b][lane];
        acc1[b] += red[u][16 + b][lane];
      }
    #pragma unroll
    for (int b = 0; b < 16; ++b) {
      gl[2 * qp][j][b] = acc0[b];       // qp=0: i,f ; qp=1: g,o
      gl[2 * qp + 1][j][b] = acc1[b];
    }
  }
  __syncthreads();

  // cell update: thread -> cells (bl, jb) and (bl+8, jb)
  const int jb = tid & 31;
  const int bl = tid >> 5;
  const int jgl = js * 32 + jb;
  const float* xgp = dir ? xgb : xgf;

  #pragma unroll
  for (int u = 0; u < 2; ++u) {
    const int b = bl + u * 8;
    const int bg = bc * 16 + b;
    const size_t xbase = ((size_t)r * 256 + bg) * 1024 + jgl;
    float gi = gl[0][jb][b] + xgp[xbase];
    float gf = gl[1][jb][b] + xgp[xbase + 256];
    float gg = gl[2][jb][b] + xgp[xbase + 512];
    float go = gl[3][jb][b] + xgp[xbase + 768];
    gi = 1.f / (1.f + expf(-gi));
    gf = 1.f / (1.f + expf(-gf));
    gg = tanhf(gg);
    go = 1.f / (1.f + expf(-go));
    const size_t cidx = ((size_t)dir * 256 + bg) * 256 + jgl;
    float c_old = c_state[cidx];
    float c_new = gf * c_old + gi * gg;
    float h_new = go * tanhf(c_new);
    float h_old = h_lds[b * 256 + jgl];
    bool mk = tt < blen[bg];
    c_state[cidx] = mk ? c_new : c_old;
    h_state[(((size_t)((1 - slot) * 2 + dir) * 256) + bg) * 256 + jgl] = mk ? h_new : h_old;
    h_out[(((size_t)dir * 200 + tt) * 256 + bg) * 256 + jgl] = mk ? h_new : 0.f;
  }
}

// ---------------- feats[b][t][k] = [hf|hb] . W_tag[k] + b_tag[k]
__global__ __launch_bounds__(256) void feats_kernel(
    const float* __restrict__ h_out, const float* __restrict__ wtag,
    const float* __restrict__ btag, float* __restrict__ feats) {
  __shared__ float hcat[32][512];
  const int t = blockIdx.x, bc = blockIdx.y;
  const int tid = threadIdx.x;
  const float* hf = h_out + (((size_t)0 * 200 + t) * 256 + bc * 32) * 256;
  const float* hb = h_out + (((size_t)1 * 200 + t) * 256 + bc * 32) * 256;
  for (int i = tid; i < 2048; i += 256) {
    int row = i >> 6, c4 = (i & 63) << 2;
    *(float4*)&hcat[row][c4] = *(const float4*)(hf + (size_t)row * 256 + c4);
    *(float4*)&hcat[row][256 + c4] = *(const float4*)(hb + (size_t)row * 256 + c4);
  }
  __syncthreads();
  const int kk = tid & 63;
  const int bg = tid >> 6;
  if (kk < 52) {
    float acc[8];
    #pragma unroll
    for (int i = 0; i < 8; ++i) acc[i] = 0.f;
    const float* wr = wtag + (size_t)kk * 512;
    for (int jq = 0; jq < 128; ++jq) {
      float4 wv = *(const float4*)(wr + jq * 4);
      #pragma unroll
      for (int bi = 0; bi < 8; ++bi) {
        float4 hv = *(const float4*)&hcat[bg * 8 + bi][jq * 4];
        acc[bi] += wv.x * hv.x + wv.y * hv.y + wv.z * hv.z + wv.w * hv.w;
      }
    }
    float bv = btag[kk];
    #pragma unroll
    for (int bi = 0; bi < 8; ++bi)
      feats[(size_t)(bc * 32 + bg * 8 + bi) * 10400 + t * 52 + kk] = acc[bi] + bv;
  }
}

// ---------------- Viterbi: one WG per batch row; bp kept in LDS; np semantics.
__global__ __launch_bounds__(256) void viterbi_kernel(
    const float* __restrict__ feats, const float* __restrict__ trans,
    const int* __restrict__ blen, float* __restrict__ out) {
  const int b = blockIdx.x;
  const int tid = threadIdx.x;
  const int k = tid & 63;
  const int g = tid >> 6;
  __shared__ float trl[52 * 52];
  __shared__ float part[52];
  __shared__ float redv[4][64];
  __shared__ int redi[4][64];
  __shared__ int bp[199][52];
  __shared__ float finals[64];

  for (int i = tid; i < 2704; i += 256) trl[i] = trans[i];
  const float* fb = feats + (size_t)b * 10400;
  const int len = blen[b];
  __syncthreads();
  if (tid < 52) part[tid] = trl[50 * 52 + tid] + fb[tid];   // START row = 50
  __syncthreads();

  for (int t = 1; t < 200; ++t) {
    float mv = -1e30f;
    int mj = 0;
    if (k < 52) {
      const float ftk = fb[t * 52 + k];
      #pragma unroll
      for (int jj = 0; jj < 13; ++jj) {
        const int jdx = g * 13 + jj;
        float cand = (part[jdx] + trl[jdx * 52 + k]) + ftk;  // np eval order
        if (cand > mv) { mv = cand; mj = jdx; }              // first-index ties
      }
    }
    redv[g][k] = mv;
    redi[g][k] = mj;
    __syncthreads();
    if (g == 0 && k < 52) {
      float bv = redv[0][k]; int bj = redi[0][k];
      #pragma unroll
      for (int u = 1; u < 4; ++u)
        if (redv[u][k] > bv) { bv = redv[u][k]; bj = redi[u][k]; }
      bool m = t < len;
      bp[t - 1][k] = m ? bj : k;     // ident when masked
      if (m) part[k] = bv;
    }
    __syncthreads();
  }

  if (g == 0 && k < 52) finals[k] = part[k] + trl[k * 52 + 51];  // STOP col = 51
  __syncthreads();
  if (tid == 0) {
    float bs = finals[0]; int bt = 0;
    for (int kk2 = 1; kk2 < 52; ++kk2)
      if (finals[kk2] > bs) { bs = finals[kk2]; bt = kk2; }
    out[b] = bs;
    int tag = bt;
    float* dec = out + 256 + (size_t)b * 200;
    dec[199] = (199 < len) ? (float)tag : 0.f;
    for (int i = 198; i >= 0; --i) {
      tag = bp[i][tag];
      dec[i] = (i < len) ? (float)tag : 0.f;
    }
  }
}

extern "C" void kernel_launch(void* const* d_in, const int* in_sizes, int n_in,
                              void* d_out, int out_size, void* d_ws, size_t ws_size,
                              hipStream_t stream) {
  const int*   bin  = (const int*)d_in[0];
  const int*   bfe  = (const int*)d_in[1];
  const int*   blen = (const int*)d_in[2];
  // d_in[3] batch_recover: unused. d_in[4] mask: derived from batch_len.
  const float* ctab = (const float*)d_in[5];
  const float* ftab = (const float*)d_in[6];
  const float* wihf = (const float*)d_in[7];
  const float* whhf = (const float*)d_in[8];
  const float* bf   = (const float*)d_in[9];
  const float* wihb = (const float*)d_in[10];
  const float* whhb = (const float*)d_in[11];
  const float* bb   = (const float*)d_in[12];
  const float* wtag = (const float*)d_in[13];
  const float* btag = (const float*)d_in[14];
  const float* trn  = (const float*)d_in[15];

  // ---- workspace layout (floats), sized to fit ws_size ----
  // fixed: hst 262144 + cst 131072 + hout 26214400 + fts 2662400 = 29,270,016 f (117.1 MB)
  // xg:    2 * C * 262144 f  (2C MB). Pick largest divisor-of-200 C that fits.
  const size_t FIXED_F = 29270016;
  size_t ws_f = ws_size / sizeof(float);
  int C = 1;
  const int cands[8] = {25, 20, 10, 8, 5, 4, 2, 1};
  for (int u = 0; u < 8; ++u) {
    if (FIXED_F + (size_t)2 * cands[u] * 262144 <= ws_f) { C = cands[u]; break; }
  }

  float* ws  = (float*)d_ws;
  float* xgf = ws;                          // C * 262144
  float* xgb = xgf + (size_t)C * 262144;    // C * 262144
  float* hst = xgb + (size_t)C * 262144;    // 262,144 (2 slots x 2 dir x 256 x 256)
  float* cst = hst + 262144;                // 131,072
  float* hout = cst + 131072;               // 26,214,400 (2 dir x 200 x 256 x 256)
  float* fts  = hout + 26214400;            // 2,662,400
  float* out  = (float*)d_out;

  hipMemsetAsync(hst, 0, (size_t)(262144 + 131072) * sizeof(float), stream);

  const int nchunks = 200 / C;
  for (int c = 0; c < nchunks; ++c) {
    // forward chunk: local row r holds t = c*C + r
    xg_gemm<<<dim3(4 * C, 8), 256, 0, stream>>>(bin, bfe, ctab, ftab, wihf, bf,
                                                xgf, c * C, 1);
    // backward chunk: local row r holds t = (199 - c*C) - r
    xg_gemm<<<dim3(4 * C, 8), 256, 0, stream>>>(bin, bfe, ctab, ftab, wihb, bb,
                                                xgb, 199 - c * C, -1);
    for (int r = 0; r < C; ++r) {
      int s = c * C + r;
      lstm_step<<<dim3(16, 8, 2), 256, 0, stream>>>(xgf, xgb, whhf, whhb, blen,
                                                    hst, cst, hout, s, r);
    }
  }
  feats_kernel<<<dim3(200, 8), 256, 0, stream>>>(hout, wtag, btag, fts);
  viterbi_kernel<<<256, 256, 0, stream>>>(fts, trn, blen, out);
}